// Round 2
// baseline (736.812 us; speedup 1.0000x reference)
//
#include <hip/hip_runtime.h>
#include <hip/hip_bf16.h>
#include <math.h>

#define NUM_EMB 32
#define ADIM 32
#define HID 1024
#define BB 128
#define TT 64
#define MAXT 80   // max tasks: sum ceil(c_i/2) <= 128/2 + 32/2 = 80

typedef __attribute__((ext_vector_type(8))) __bf16 bf16x8;
typedef __attribute__((ext_vector_type(4))) float floatx4;

// ---------- K0: counting sort + same-cat pairing into task list ----------
// task = (b0, b1|-1, cat, 0). All 80 slots written (ws is re-poisoned).
__global__ void task_kernel(const int* __restrict__ cats, int4* __restrict__ tasks) {
  __shared__ int cnt[NUM_EMB];
  __shared__ int pos[NUM_EMB];
  __shared__ int pv[BB];
  int tid = threadIdx.x;
  if (tid < NUM_EMB) cnt[tid] = 0;
  __syncthreads();
  if (tid < BB) atomicAdd(&cnt[cats[tid]], 1);
  __syncthreads();
  if (tid == 0) {
    int run = 0;
    for (int c = 0; c < NUM_EMB; ++c) { pos[c] = run; run += cnt[c]; }
  }
  __syncthreads();
  if (tid < BB) {
    int p = atomicAdd(&pos[cats[tid]], 1);
    pv[p] = tid;
  }
  __syncthreads();
  if (tid == 0) {
    int t = 0, off = 0;
    for (int c = 0; c < NUM_EMB; ++c) {
      for (int i = 0; i < cnt[c]; i += 2) {
        int b0 = pv[off + i];
        int b1 = (i + 1 < cnt[c]) ? pv[off + i + 1] : -1;
        tasks[t++] = make_int4(b0, b1, c, 0);
      }
      off += cnt[c];
    }
    for (; t < MAXT; ++t) tasks[t] = make_int4(-1, -1, 0, 0);
  }
}

// ---------- K1: GEMM1 (fp32, K=32) + sinusoidal tau -> x2 bf16 ----------
// Block: one b, 16 t-rows; 256 threads, 4 h-cols x 16 rows per thread.
__global__ __launch_bounds__(256) void embed_kernel(
    const float* __restrict__ actions, const float* __restrict__ timesteps,
    const float* __restrict__ W1w, const float* __restrict__ W1b,
    const int* __restrict__ cats, __bf16* __restrict__ x2) {
  const int b = blockIdx.y;
  const int t0 = blockIdx.x * 16;
  const int cat = cats[b];
  const int tid = threadIdx.x;

  __shared__ float act[16][ADIM];
  {
    int row = tid >> 5, k = tid & 31;               // 8 rows per 256 threads
    act[row][k] = actions[((size_t)(b * TT + t0 + row)) * ADIM + k];
    act[row + 8][k] = actions[((size_t)(b * TT + t0 + row + 8)) * ADIM + k];
  }
  __syncthreads();

  const float* W = W1w + (size_t)cat * ADIM * HID;
  float acc[4][16];
#pragma unroll
  for (int ii = 0; ii < 4; ++ii) {
    float bv = W1b[cat * HID + tid + ii * 256];
#pragma unroll
    for (int tt = 0; tt < 16; ++tt) acc[ii][tt] = bv;
  }
  for (int k = 0; k < ADIM; ++k) {
#pragma unroll
    for (int ii = 0; ii < 4; ++ii) {
      float w = W[k * HID + tid + ii * 256];
#pragma unroll
      for (int tt = 0; tt < 16; ++tt) acc[ii][tt] += act[tt][k] * w;
    }
  }
#pragma unroll
  for (int ii = 0; ii < 4; ++ii) {
    int hcol = tid + ii * 256;
#pragma unroll
    for (int tt = 0; tt < 16; ++tt)
      x2[((size_t)(b * TT + t0 + tt)) * 2048 + hcol] = (__bf16)acc[ii][tt];
  }
  // tau half
  float tb = timesteps[b];
  const float kLog = 9.210340371976184f;  // ln(10000)
#pragma unroll
  for (int ii = 0; ii < 4; ++ii) {
    int j = tid + ii * 256;
    int jj = (j < 512) ? j : (j - 512);
    float freq = tb * expf(-kLog * (float)jj * (1.0f / 512.0f));
    float v = (j < 512) ? sinf(freq) : cosf(freq);
    __bf16 hv = (__bf16)v;
#pragma unroll
    for (int tt = 0; tt < 16; ++tt)
      x2[((size_t)(b * TT + t0 + tt)) * 2048 + 1024 + j] = hv;
  }
}

// ---------- K2/K3: paired-category bf16 MFMA GEMM ----------
// Task block: M = 128 (b0 rows 0..63, b1 rows 64..127), N = 128, Kstep = 32.
// 256 threads = 4 waves; wave w covers cols [w*32, w*32+32).
// A-frags loaded DIRECT from global (bf16, k-contig, L1-resident).
// B staged in LDS (n-major, stride 40 el): thread loads 2n x 8k as 8 float2
// (coalesced rows), cvt, 2x ds_write_b128; register-prefetched one K-step
// ahead so global latency hides under the 16-MFMA compute phase.
template <bool SILU, bool OUT_BF16, int K>
__global__ __launch_bounds__(256, 2) void gemm_kernel(
    const __bf16* __restrict__ A, const float* __restrict__ Wbase,
    const float* __restrict__ bias, const int4* __restrict__ tasks,
    void* __restrict__ Out) {
  const int4 task = tasks[blockIdx.y];
  const int b0 = task.x, b1 = task.y, cat = task.z;
  if (b0 < 0) return;
  const int nb = blockIdx.x * 128;
  const int tid = threadIdx.x;
  const int w = tid >> 6, lane = tid & 63, q = lane >> 4, r = lane & 15;

  __shared__ __attribute__((aligned(16))) __bf16 Bs[128 * 40];

  const float* W = Wbase + (size_t)cat * K * HID + nb;
  const __bf16* A0 = A + (size_t)b0 * TT * K;
  const __bf16* A1 = (b1 >= 0) ? (A + (size_t)b1 * TT * K) : A0;

  floatx4 acc[8][2];
#pragma unroll
  for (int mt = 0; mt < 8; ++mt)
#pragma unroll
    for (int nt = 0; nt < 2; ++nt) acc[mt][nt] = (floatx4){0.f, 0.f, 0.f, 0.f};

  const int ln = (tid & 63) * 2;  // B n-pair
  const int kb = tid >> 6;        // B k-octet

  // prologue prefetch (k0 = 0)
  float2 bv[8];
  {
    const float* Wp = W + (size_t)(kb * 8) * HID + ln;
#pragma unroll
    for (int j = 0; j < 8; ++j)
      bv[j] = *reinterpret_cast<const float2*>(Wp + (size_t)j * HID);
  }

  for (int k0 = 0; k0 < K; k0 += 32) {
    __syncthreads();  // previous iteration's frag reads done
    union { uint4 u; __bf16 h[8]; } t0, t1;
#pragma unroll
    for (int j = 0; j < 8; ++j) { t0.h[j] = (__bf16)bv[j].x; t1.h[j] = (__bf16)bv[j].y; }
    *reinterpret_cast<uint4*>(&Bs[ln * 40 + kb * 8]) = t0.u;
    *reinterpret_cast<uint4*>(&Bs[(ln + 1) * 40 + kb * 8]) = t1.u;
    __syncthreads();

    // prefetch next K-step (consumed after the MFMA phase -> latency hidden)
    if (k0 + 32 < K) {
      const float* Wp = W + (size_t)(k0 + 32 + kb * 8) * HID + ln;
#pragma unroll
      for (int j = 0; j < 8; ++j)
        bv[j] = *reinterpret_cast<const float2*>(Wp + (size_t)j * HID);
    }

    bf16x8 bfrag[2];
#pragma unroll
    for (int nt = 0; nt < 2; ++nt)
      bfrag[nt] = *reinterpret_cast<const bf16x8*>(&Bs[(w * 32 + nt * 16 + r) * 40 + q * 8]);

#pragma unroll
    for (int mt = 0; mt < 4; ++mt) {
      bf16x8 afrag = *reinterpret_cast<const bf16x8*>(A0 + (size_t)(mt * 16 + r) * K + k0 + q * 8);
      acc[mt][0] = __builtin_amdgcn_mfma_f32_16x16x32_bf16(afrag, bfrag[0], acc[mt][0], 0, 0, 0);
      acc[mt][1] = __builtin_amdgcn_mfma_f32_16x16x32_bf16(afrag, bfrag[1], acc[mt][1], 0, 0, 0);
    }
    if (b1 >= 0) {
#pragma unroll
      for (int mt = 4; mt < 8; ++mt) {
        bf16x8 afrag = *reinterpret_cast<const bf16x8*>(A1 + (size_t)((mt - 4) * 16 + r) * K + k0 + q * 8);
        acc[mt][0] = __builtin_amdgcn_mfma_f32_16x16x32_bf16(afrag, bfrag[0], acc[mt][0], 0, 0, 0);
        acc[mt][1] = __builtin_amdgcn_mfma_f32_16x16x32_bf16(afrag, bfrag[1], acc[mt][1], 0, 0, 0);
      }
    }
  }

  // epilogue: D row = q*4+rr (m), col = r (n)  [m89/m91-verified]
#pragma unroll
  for (int nt = 0; nt < 2; ++nt) {
    int col = nb + w * 32 + nt * 16 + r;
    float bvv = bias[cat * HID + col];
#pragma unroll
    for (int mt = 0; mt < 8; ++mt) {
      if (mt >= 4 && b1 < 0) break;
      int b = (mt < 4) ? b0 : b1;
#pragma unroll
      for (int rr = 0; rr < 4; ++rr) {
        int m = (mt & 3) * 16 + q * 4 + rr;
        float v = acc[mt][nt][rr] + bvv;
        if (SILU) v = v / (1.0f + expf(-v));
        size_t oidx = ((size_t)(b * TT + m)) * HID + col;
        if (OUT_BF16) ((__bf16*)Out)[oidx] = (__bf16)v;
        else ((float*)Out)[oidx] = v;
      }
    }
  }
}

// ---------- launcher ----------
extern "C" void kernel_launch(void* const* d_in, const int* in_sizes, int n_in,
                              void* d_out, int out_size, void* d_ws, size_t ws_size,
                              hipStream_t stream) {
  const float* actions = (const float*)d_in[0];
  const float* timesteps = (const float*)d_in[1];
  const float* W1w = (const float*)d_in[2];
  const float* W1b = (const float*)d_in[3];
  const float* W2w = (const float*)d_in[4];
  const float* W2b = (const float*)d_in[5];
  const float* W3w = (const float*)d_in[6];
  const float* W3b = (const float*)d_in[7];
  const int* cats = (const int*)d_in[8];
  float* out = (float*)d_out;

  char* ws = (char*)d_ws;
  __bf16* x2 = (__bf16*)ws;                       // 128*64*2048*2 = 33,554,432 B
  __bf16* h = (__bf16*)(ws + 33554432);           // 128*64*1024*2 = 16,777,216 B
  int4* tasks = (int4*)(ws + 33554432 + 16777216);

  task_kernel<<<1, 128, 0, stream>>>(cats, tasks);
  embed_kernel<<<dim3(4, BB), 256, 0, stream>>>(actions, timesteps, W1w, W1b, cats, x2);
  gemm_kernel<true, true, 2048><<<dim3(8, MAXT), 256, 0, stream>>>(x2, W2w, W2b, tasks, (void*)h);
  gemm_kernel<false, false, 1024><<<dim3(8, MAXT), 256, 0, stream>>>(h, W3w, W3b, tasks, (void*)out);
}

// Round 3
// 574.047 us; speedup vs baseline: 1.2835x; 1.2835x over previous
//
#include <hip/hip_runtime.h>
#include <hip/hip_bf16.h>
#include <math.h>

#define NUM_EMB 32
#define ADIM 32
#define HID 1024
#define BB 128
#define TT 64
#define MAXT 80   // max tasks: sum ceil(c_i/2) <= 64 + 16 = 80

typedef __attribute__((ext_vector_type(8))) __bf16 bf16x8;
typedef __attribute__((ext_vector_type(4))) float floatx4;

// ---------- K0: counting sort + same-cat pairing into task list ----------
__global__ void task_kernel(const int* __restrict__ cats, int4* __restrict__ tasks) {
  __shared__ int cnt[NUM_EMB];
  __shared__ int pos[NUM_EMB];
  __shared__ int pv[BB];
  int tid = threadIdx.x;
  if (tid < NUM_EMB) cnt[tid] = 0;
  __syncthreads();
  if (tid < BB) atomicAdd(&cnt[cats[tid]], 1);
  __syncthreads();
  if (tid == 0) {
    int run = 0;
    for (int c = 0; c < NUM_EMB; ++c) { pos[c] = run; run += cnt[c]; }
  }
  __syncthreads();
  if (tid < BB) {
    int p = atomicAdd(&pos[cats[tid]], 1);
    pv[p] = tid;
  }
  __syncthreads();
  if (tid == 0) {
    int t = 0, off = 0;
    for (int c = 0; c < NUM_EMB; ++c) {
      for (int i = 0; i < cnt[c]; i += 2) {
        int b0 = pv[off + i];
        int b1 = (i + 1 < cnt[c]) ? pv[off + i + 1] : -1;
        tasks[t++] = make_int4(b0, b1, c, 0);
      }
      off += cnt[c];
    }
    for (; t < MAXT; ++t) tasks[t] = make_int4(-1, -1, 0, 0);
  }
}

// ---------- K1: GEMM1 (fp32, K=32) + sinusoidal tau -> x2 bf16 ----------
__global__ __launch_bounds__(256) void embed_kernel(
    const float* __restrict__ actions, const float* __restrict__ timesteps,
    const float* __restrict__ W1w, const float* __restrict__ W1b,
    const int* __restrict__ cats, __bf16* __restrict__ x2) {
  const int b = blockIdx.y;
  const int t0 = blockIdx.x * 16;
  const int cat = cats[b];
  const int tid = threadIdx.x;

  __shared__ float act[16][ADIM];
  {
    int row = tid >> 5, k = tid & 31;
    act[row][k] = actions[((size_t)(b * TT + t0 + row)) * ADIM + k];
    act[row + 8][k] = actions[((size_t)(b * TT + t0 + row + 8)) * ADIM + k];
  }
  __syncthreads();

  const float* W = W1w + (size_t)cat * ADIM * HID;
  float acc[4][16];
#pragma unroll
  for (int ii = 0; ii < 4; ++ii) {
    float bv = W1b[cat * HID + tid + ii * 256];
#pragma unroll
    for (int tt = 0; tt < 16; ++tt) acc[ii][tt] = bv;
  }
  for (int k = 0; k < ADIM; ++k) {
#pragma unroll
    for (int ii = 0; ii < 4; ++ii) {
      float w = W[k * HID + tid + ii * 256];
#pragma unroll
      for (int tt = 0; tt < 16; ++tt) acc[ii][tt] += act[tt][k] * w;
    }
  }
#pragma unroll
  for (int ii = 0; ii < 4; ++ii) {
    int hcol = tid + ii * 256;
#pragma unroll
    for (int tt = 0; tt < 16; ++tt)
      x2[((size_t)(b * TT + t0 + tt)) * 2048 + hcol] = (__bf16)acc[ii][tt];
  }
  float tb = timesteps[b];
  const float kLog = 9.210340371976184f;  // ln(10000)
#pragma unroll
  for (int ii = 0; ii < 4; ++ii) {
    int j = tid + ii * 256;
    int jj = (j < 512) ? j : (j - 512);
    float freq = tb * expf(-kLog * (float)jj * (1.0f / 512.0f));
    float v = (j < 512) ? sinf(freq) : cosf(freq);
    __bf16 hv = (__bf16)v;
#pragma unroll
    for (int tt = 0; tt < 16; ++tt)
      x2[((size_t)(b * TT + t0 + tt)) * 2048 + 1024 + j] = hv;
  }
}

// ---------- K2/K3: paired-category bf16 MFMA GEMM, SW-pipelined ----------
// M=128 (b0 rows 0..63, b1 rows 64..127), N=128, Kstep=32, 4 waves.
// A and B staged in LDS (row stride 40 el = 80 B: every b128 access maps
// 64 lanes to 8 row-start banks x 4-bank span = optimal 8-phase schedule).
// Register prefetch of NEXT k-step (A: 2x dwordx4, B: 16 coalesced dwords)
// issued right after the write-barrier, consumed next iteration -> global
// latency drains under frag reads + 16 MFMAs.
// If task unpaired (b1<0): compute duplicates b0 in mt>=4, stores guarded.
template <bool SILU, bool OUT_BF16, int K>
__global__ __launch_bounds__(256, 3) void gemm_kernel(
    const __bf16* __restrict__ A, const float* __restrict__ Wbase,
    const float* __restrict__ bias, const int4* __restrict__ tasks,
    void* __restrict__ Out) {
  const int4 task = tasks[blockIdx.y];
  const int b0 = task.x, b1s = task.y, cat = task.z;
  if (b0 < 0) return;
  const int b1 = (b1s >= 0) ? b1s : b0;
  const int nb = blockIdx.x * 128;
  const int tid = threadIdx.x;
  const int w = tid >> 6, lane = tid & 63, q = lane >> 4, r = lane & 15;

  __shared__ __attribute__((aligned(16))) __bf16 As[128 * 40];
  __shared__ __attribute__((aligned(16))) __bf16 Bs[128 * 40];

  const float* W = Wbase + (size_t)cat * K * HID + nb;
  const __bf16* A0 = A + (size_t)b0 * TT * K;
  const __bf16* A1 = A + (size_t)b1 * TT * K;

  floatx4 acc[8][2];
#pragma unroll
  for (int mt = 0; mt < 8; ++mt)
#pragma unroll
    for (int nt = 0; nt < 2; ++nt) acc[mt][nt] = (floatx4){0.f, 0.f, 0.f, 0.f};

  const int bn = tid & 127;   // B col -> LDS row (1 row/thread: optimal banks)
  const int bkq = tid >> 7;   // 0..1; octets {bkq, bkq+2}
  const int am = tid >> 2;    // 0..63 A row (both halves)
  const int ac = tid & 3;     // 16B chunk in 32-k row

  float bv[2][8];
  uint4 a0v, a1v;

  {  // prologue prefetch k0=0
#pragma unroll
    for (int i = 0; i < 2; ++i) {
      const float* Wp = W + (size_t)((bkq + 2 * i) * 8) * HID + bn;
#pragma unroll
      for (int j = 0; j < 8; ++j) bv[i][j] = Wp[(size_t)j * HID];
    }
    a0v = *reinterpret_cast<const uint4*>(A0 + (size_t)am * K + ac * 8);
    a1v = *reinterpret_cast<const uint4*>(A1 + (size_t)am * K + ac * 8);
  }

  for (int k0 = 0; k0 < K; k0 += 32) {
    __syncthreads();  // prev iteration's frag reads done
    *reinterpret_cast<uint4*>(&As[am * 40 + ac * 8]) = a0v;
    *reinterpret_cast<uint4*>(&As[(am + 64) * 40 + ac * 8]) = a1v;
#pragma unroll
    for (int i = 0; i < 2; ++i) {
      union { uint4 u; __bf16 h[8]; } t;
#pragma unroll
      for (int j = 0; j < 8; ++j) t.h[j] = (__bf16)bv[i][j];
      *reinterpret_cast<uint4*>(&Bs[bn * 40 + (bkq + 2 * i) * 8]) = t.u;
    }
    __syncthreads();

    if (k0 + 32 < K) {  // prefetch next k-step; drains under MFMA phase
      const int kn = k0 + 32;
#pragma unroll
      for (int i = 0; i < 2; ++i) {
        const float* Wp = W + (size_t)(kn + (bkq + 2 * i) * 8) * HID + bn;
#pragma unroll
        for (int j = 0; j < 8; ++j) bv[i][j] = Wp[(size_t)j * HID];
      }
      a0v = *reinterpret_cast<const uint4*>(A0 + (size_t)am * K + kn + ac * 8);
      a1v = *reinterpret_cast<const uint4*>(A1 + (size_t)am * K + kn + ac * 8);
    }

    bf16x8 bfrag[2];
#pragma unroll
    for (int nt = 0; nt < 2; ++nt)
      bfrag[nt] = *reinterpret_cast<const bf16x8*>(&Bs[(w * 32 + nt * 16 + r) * 40 + q * 8]);
#pragma unroll
    for (int mt = 0; mt < 8; ++mt) {
      bf16x8 afrag = *reinterpret_cast<const bf16x8*>(&As[(mt * 16 + r) * 40 + q * 8]);
      acc[mt][0] = __builtin_amdgcn_mfma_f32_16x16x32_bf16(afrag, bfrag[0], acc[mt][0], 0, 0, 0);
      acc[mt][1] = __builtin_amdgcn_mfma_f32_16x16x32_bf16(afrag, bfrag[1], acc[mt][1], 0, 0, 0);
    }
  }

  // epilogue: D row = q*4+rr (m), col = r (n)  [m89/m91-verified]
#pragma unroll
  for (int nt = 0; nt < 2; ++nt) {
    int col = nb + w * 32 + nt * 16 + r;
    float bvv = bias[cat * HID + col];
#pragma unroll
    for (int mt = 0; mt < 8; ++mt) {
      if (mt >= 4 && b1s < 0) break;
      int b = (mt < 4) ? b0 : b1;
#pragma unroll
      for (int rr = 0; rr < 4; ++rr) {
        int m = (mt & 3) * 16 + q * 4 + rr;
        float v = acc[mt][nt][rr] + bvv;
        if (SILU) v = v / (1.0f + expf(-v));
        size_t oidx = ((size_t)(b * TT + m)) * HID + col;
        if (OUT_BF16) ((__bf16*)Out)[oidx] = (__bf16)v;
        else ((float*)Out)[oidx] = v;
      }
    }
  }
}

// ---------- launcher ----------
extern "C" void kernel_launch(void* const* d_in, const int* in_sizes, int n_in,
                              void* d_out, int out_size, void* d_ws, size_t ws_size,
                              hipStream_t stream) {
  const float* actions = (const float*)d_in[0];
  const float* timesteps = (const float*)d_in[1];
  const float* W1w = (const float*)d_in[2];
  const float* W1b = (const float*)d_in[3];
  const float* W2w = (const float*)d_in[4];
  const float* W2b = (const float*)d_in[5];
  const float* W3w = (const float*)d_in[6];
  const float* W3b = (const float*)d_in[7];
  const int* cats = (const int*)d_in[8];
  float* out = (float*)d_out;

  char* ws = (char*)d_ws;
  __bf16* x2 = (__bf16*)ws;                       // 33,554,432 B
  __bf16* h = (__bf16*)(ws + 33554432);           // 16,777,216 B
  int4* tasks = (int4*)(ws + 33554432 + 16777216);

  task_kernel<<<1, 128, 0, stream>>>(cats, tasks);
  embed_kernel<<<dim3(4, BB), 256, 0, stream>>>(actions, timesteps, W1w, W1b, cats, x2);
  gemm_kernel<true, true, 2048><<<dim3(8, MAXT), 256, 0, stream>>>(x2, W2w, W2b, tasks, (void*)h);
  gemm_kernel<false, false, 1024><<<dim3(8, MAXT), 256, 0, stream>>>(h, W3w, W3b, tasks, (void*)out);
}